// Round 9
// baseline (95.632 us; speedup 1.0000x reference)
//
#include <hip/hip_runtime.h>

// Weighted Chamfer, B=4, N=M=8192, D=3, fp32 in/out.
// out = (1/B)*[ sum_b sum_n w*min_m d2 + sum_b sum_m min_n d2 ]
//
// One v_mfma_f32_32x32x16_bf16 yields a 32x32 tile of d2 = s2 + t2 - 2 s.t
// via K-slot packing with split-bf16 compensation (verified rounds 2-8):
//   k0-8: {hs,hs,ls}x * {-2ht,-2lt,-2ht}x per dim; k9-10: {h,l}(s2)*1;
//   k11-12: 1*{h,l}(t2); k13-15: zero.  Error ~1e-5 (threshold 5.76).
// C/D layout (m74/m101): col=lane&31, row=(reg&3)+8*(reg>>2)+4*(lane>>5).
//
// Round 9: DIAGNOSTIC. r8's scan (~28 us by subtraction) hides below the five
// 42-us ws-re-poison fills in rocprof top-5, so no scan counters since r4.
// This round adds a REP=2 grid dimension: two block-sets do byte-identical
// work and write identical values (race-safe) -> one ~56 us scan dispatch
// surfaces in top-5 WITH VGPR_Count / Occupancy / MfmaUtil / VALUBusy /
// LDS-conflict counters. Kernel body is byte-identical to r8, so the
// counters describe the kernel we keep. Total regresses ~+28 us this round.

typedef short bf16x8 __attribute__((ext_vector_type(8)));
typedef float f32x16 __attribute__((ext_vector_type(16)));

#define BB 4
#define NP 8192
#define NFRAG (NP / 32)          // 256 32-point fragments per batch
#define RF 4                     // query-frags per wave (128 queries)
#define WAVES 4                  // 256 threads; 512 queries per block
#define QBLOCKS 16               // 8192 / 512
#define CFRAGS 32                // DB frags per LDS stage (1024 pts, 32 KB)
#define NCHG 8                   // DB chunks (8192 / 1024)
#define REP 2                    // diagnostic work multiplier

__device__ __forceinline__ unsigned short bf16r(float x) {
    unsigned u = __float_as_uint(x);
    unsigned r = u + 0x7FFFu + ((u >> 16) & 1u);
    return (unsigned short)(r >> 16);
}
__device__ __forceinline__ float bf16f(unsigned short h) {
    return __uint_as_float(((unsigned)h) << 16);
}

// ---- prep: A-pack and B-pack (32x32x16 fragment layout) for both clouds ----
__global__ __launch_bounds__(256) void prep_kernel(
    const float* __restrict__ src, const float* __restrict__ tgt,
    uint4* __restrict__ aS, uint4* __restrict__ bS,
    uint4* __restrict__ aT, uint4* __restrict__ bT,
    float* __restrict__ out)
{
    int gid = blockIdx.x * 256 + threadIdx.x;   // 2*4*256*64 = 131072
    if (gid == 0) out[0] = 0.0f;
    int cloud = gid >> 16;
    int rem   = gid & 65535;
    int b     = rem >> 14;
    int f     = (rem >> 6) & (NFRAG - 1);
    int lane  = rem & 63;
    int half  = lane >> 5;
    int p     = f * 32 + (lane & 31);

    const float* c = cloud ? tgt : src;
    size_t base = ((size_t)b * NP + p) * 3;
    float x = c[base + 0], y = c[base + 1], z = c[base + 2];
    float n2 = x * x + y * y + z * z;

    unsigned short hx = bf16r(x), lx = bf16r(x - bf16f(hx));
    unsigned short hy = bf16r(y), ly = bf16r(y - bf16f(hy));
    unsigned short hz = bf16r(z), lz = bf16r(z - bf16f(hz));
    unsigned short h2 = bf16r(n2), l2 = bf16r(n2 - bf16f(h2));
    unsigned short nhx = bf16r(-2.f * bf16f(hx)), nlx = bf16r(-2.f * bf16f(lx));
    unsigned short nhy = bf16r(-2.f * bf16f(hy)), nly = bf16r(-2.f * bf16f(ly));
    unsigned short nhz = bf16r(-2.f * bf16f(hz)), nlz = bf16r(-2.f * bf16f(lz));
    const unsigned ONE = 0x3F80u;

    uint4 pa, pb;
    if (half == 0) {   // k = 0..7
        pa.x = (unsigned)hx | ((unsigned)hx << 16);
        pa.y = (unsigned)lx | ((unsigned)hy << 16);
        pa.z = (unsigned)hy | ((unsigned)ly << 16);
        pa.w = (unsigned)hz | ((unsigned)hz << 16);
        pb.x = (unsigned)nhx | ((unsigned)nlx << 16);
        pb.y = (unsigned)nhx | ((unsigned)nhy << 16);
        pb.z = (unsigned)nly | ((unsigned)nhy << 16);
        pb.w = (unsigned)nhz | ((unsigned)nlz << 16);
    } else {           // k = 8..15 (13..15 zero)
        pa.x = (unsigned)lz | ((unsigned)h2 << 16);
        pa.y = (unsigned)l2 | (ONE << 16);
        pa.z = ONE;
        pa.w = 0u;
        pb.x = (unsigned)nhz | (ONE << 16);
        pb.y = ONE | ((unsigned)h2 << 16);
        pb.z = (unsigned)l2;
        pb.w = 0u;
    }
    size_t off = ((size_t)b * NFRAG + f) * 64 + lane;
    (cloud ? aT : aS)[off] = pa;
    (cloud ? bT : bS)[off] = pb;
}

// ---- scan: DB rows from LDS, queries in regs, per-lane scalar running min ----
__global__ __launch_bounds__(256, 4) void scan_kernel(
    const uint4* __restrict__ aS, const uint4* __restrict__ bS,
    const uint4* __restrict__ aT, const uint4* __restrict__ bT,
    float* __restrict__ part)   // part[dir][b][ch][query]
{
    __shared__ uint4 ash[CFRAGS * 64];          // 32 KB DB stage
    const int tid = threadIdx.x;
    const int lane = tid & 63, wave = tid >> 6;
    const int qb = blockIdx.x, b = blockIdx.y;
    const int ch = blockIdx.z & (NCHG - 1);
    const int dir = (blockIdx.z >> 3) & 1;
    // rep = blockIdx.z >> 4 in {0,1}: identical work + identical writes
    // (diagnostic only - makes this dispatch ~2x so it surfaces in rocprof)

    // dir 0: queries = source (B-op bS), DB = target (A-op aT); dir 1 mirrored.
    const uint4* qfr = dir ? bT : bS;
    const uint4* dfr = dir ? aS : aT;

    // stage DB chunk (32 frags, 8 uint4/thread, coalesced)
    const uint4* dsrc = dfr + ((size_t)b * NFRAG + ch * CFRAGS) * 64;
#pragma unroll
    for (int j = 0; j < 8; j++) ash[tid + j * 256] = dsrc[tid + j * 256];

    // this wave's query fragments (B operand, registers all sweep)
    const uint4* qsrc = qfr + ((size_t)b * NFRAG + qb * (WAVES * RF) + wave * RF) * 64 + lane;
    bf16x8 qfrag[RF];
#pragma unroll
    for (int rf = 0; rf < RF; rf++) {
        uint4 t = qsrc[rf * 64];
        qfrag[rf] = *(bf16x8*)&t;
    }

    float vminq[RF];
#pragma unroll
    for (int rf = 0; rf < RF; rf++) vminq[rf] = 1e30f;
    f32x16 zero = {};
    __syncthreads();                            // the block's only barrier

    for (int t = 0; t < CFRAGS; t += 2) {
        bf16x8 a0 = *(bf16x8*)&ash[t * 64 + lane];
        bf16x8 a1 = *(bf16x8*)&ash[(t + 1) * 64 + lane];
#pragma unroll
        for (int rf = 0; rf < RF; rf++) {
            f32x16 dA = __builtin_amdgcn_mfma_f32_32x32x16_bf16(a0, qfrag[rf], zero, 0, 0, 0);
            f32x16 dB = __builtin_amdgcn_mfma_f32_32x32x16_bf16(a1, qfrag[rf], zero, 0, 0, 0);
#pragma unroll
            for (int i = 0; i < 16; i++)
                vminq[rf] = fminf(fminf(dA[i], dB[i]), vminq[rf]);  // v_min3_f32
        }
    }

    // finalize: lane^32 holds the other 16 DB rows of the same query column
    float* pbase = part + ((size_t)(dir * BB + b) * NCHG + ch) * NP
                 + qb * (WAVES * RF * 32) + wave * (RF * 32);
#pragma unroll
    for (int rf = 0; rf < RF; rf++) {
        float v = fminf(vminq[rf], __shfl_xor(vminq[rf], 32, 64));
        if (lane < 32) pbase[rf * 32 + lane] = v;
    }
}

// ---- reduce: min over DB chunks, weight, sum, atomicAdd ----
__global__ __launch_bounds__(256) void reduce_kernel(
    const float* __restrict__ weights, const float* __restrict__ part,
    float* __restrict__ out)
{
    int tid = threadIdx.x;
    int gid = blockIdx.x * 256 + tid;       // 0 .. 65535
    int dir = gid >> 15;
    int r   = gid & 32767;
    int b   = r >> 13;
    int q   = r & (NP - 1);

    const float* p = part + ((size_t)(dir * BB + b) * NCHG) * NP + q;
    float mn = 1e30f;
#pragma unroll
    for (int i = 0; i < NCHG; i++) mn = fminf(mn, p[(size_t)i * NP]);
    float w = dir ? 1.0f : weights[b * NP + q];
    float v = mn * w * (1.0f / BB);
#pragma unroll
    for (int off = 32; off; off >>= 1) v += __shfl_down(v, off, 64);
    __shared__ float ls[4];
    if ((tid & 63) == 0) ls[tid >> 6] = v;
    __syncthreads();
    if (tid == 0) atomicAdd(out, ls[0] + ls[1] + ls[2] + ls[3]);
}

extern "C" void kernel_launch(void* const* d_in, const int* in_sizes, int n_in,
                              void* d_out, int out_size, void* d_ws, size_t ws_size,
                              hipStream_t stream) {
    const float* src = (const float*)d_in[0];   // (B, N, 3)
    const float* tgt = (const float*)d_in[1];   // (B, M, 3)
    const float* wgt = (const float*)d_in[2];   // (B, N)
    float* out = (float*)d_out;

    char* ws = (char*)d_ws;
    const size_t FRAG_BYTES = (size_t)BB * NFRAG * 64 * 16;   // 1 MB each
    uint4* aS = (uint4*)(ws + 0 * FRAG_BYTES);
    uint4* bS = (uint4*)(ws + 1 * FRAG_BYTES);
    uint4* aT = (uint4*)(ws + 2 * FRAG_BYTES);
    uint4* bT = (uint4*)(ws + 3 * FRAG_BYTES);
    float* part = (float*)(ws + 4 * FRAG_BYTES);              // 2 MB

    prep_kernel<<<dim3(512), dim3(256), 0, stream>>>(src, tgt, aS, bS, aT, bT, out);
    scan_kernel<<<dim3(QBLOCKS, BB, 2 * NCHG * REP), dim3(256), 0, stream>>>(aS, bS, aT, bT, part);
    reduce_kernel<<<dim3(256), dim3(256), 0, stream>>>(wgt, part, out);
}

// Round 10
// 89.362 us; speedup vs baseline: 1.0702x; 1.0702x over previous
//
#include <hip/hip_runtime.h>

// Weighted Chamfer, B=4, N=M=8192, D=3, fp32 in/out.
// out = (1/B)*[ sum_b sum_n w*min_m d2 + sum_b sum_m min_n d2 ]
//
// d2 = s2 + t2 - 2 s.t computed by ONE bf16 MFMA via K-slot packing with
// split-bf16 compensation (verified r2-r9, absmax 0):
//   k=3d+0: h_d*(-2h_d'); k=3d+1: h_d*(-2l_d'); k=3d+2: l_d*(-2h_d');
//   k9-10: {h,l}(s2)*1; k11-12: 1*{h,l}(t2); k13+: zero. Err ~1e-5 (thr 5.76).
//
// Round 10: back to 16x16x32 MFMA (D = 4 regs, not 16). r9's REP experiment
// priced r8's scan at ~25 us = ~12 throughput + ~13 latency-slack; the 3.5x
// gap of the throughput part over the 3.4 us VALU floor matches an AGPR
// round-trip tax on the two f32x16 D operands. 4-reg D keeps the whole live
// set (~70 regs) comfortably architectural. C/D layout (m89): col=lane&15,
// row=quad*4+reg -> per-lane scalar running min per query, finalize = 2 shfl.
// Transposed operands kept from r8 (DB = A in LDS, queries = B in regs).
// 2048 blocks (~8/CU queued) exploits the measured ~50% latency slack.

typedef short bf16x8 __attribute__((ext_vector_type(8)));
typedef float f32x4 __attribute__((ext_vector_type(4)));

#define BB 4
#define NP 8192
#define NFRAG16 512              // 16-point fragments per batch
#define RF 8                     // query-frags per wave (128 queries)
#define WAVES 4                  // 256 threads; 512 queries per block
#define QBLOCKS 16               // 8192 / 512
#define CFRAGS 32                // DB frags per LDS stage (512 pts, 32 KB)
#define NCHG 16                  // DB chunks (8192 / 512)

__device__ __forceinline__ unsigned short bf16r(float x) {
    unsigned u = __float_as_uint(x);
    unsigned r = u + 0x7FFFu + ((u >> 16) & 1u);
    return (unsigned short)(r >> 16);
}
__device__ __forceinline__ float bf16f(unsigned short h) {
    return __uint_as_float(((unsigned)h) << 16);
}

// ---- prep: 16x16x32 A-pack / B-pack for both clouds (quads 2,3 zero) ----
__global__ __launch_bounds__(256) void prep_kernel(
    const float* __restrict__ src, const float* __restrict__ tgt,
    uint4* __restrict__ aS, uint4* __restrict__ bS,
    uint4* __restrict__ aT, uint4* __restrict__ bT,
    float* __restrict__ out)
{
    int gid = blockIdx.x * 256 + threadIdx.x;   // 2*4*512*64 = 262144
    if (gid == 0) out[0] = 0.0f;
    int cloud = gid >> 17;
    int rem   = gid & 131071;
    int b     = rem >> 15;
    int f     = (rem >> 6) & (NFRAG16 - 1);
    int lane  = rem & 63;
    int quad  = lane >> 4;
    int p     = f * 16 + (lane & 15);

    const float* c = cloud ? tgt : src;
    size_t base = ((size_t)b * NP + p) * 3;
    float x = c[base + 0], y = c[base + 1], z = c[base + 2];
    float n2 = x * x + y * y + z * z;

    unsigned short hx = bf16r(x), lx = bf16r(x - bf16f(hx));
    unsigned short hy = bf16r(y), ly = bf16r(y - bf16f(hy));
    unsigned short hz = bf16r(z), lz = bf16r(z - bf16f(hz));
    unsigned short h2 = bf16r(n2), l2 = bf16r(n2 - bf16f(h2));
    unsigned short nhx = bf16r(-2.f * bf16f(hx)), nlx = bf16r(-2.f * bf16f(lx));
    unsigned short nhy = bf16r(-2.f * bf16f(hy)), nly = bf16r(-2.f * bf16f(ly));
    unsigned short nhz = bf16r(-2.f * bf16f(hz)), nlz = bf16r(-2.f * bf16f(lz));
    const unsigned short ONE = 0x3F80;

    unsigned short va[8] = {0,0,0,0,0,0,0,0};
    unsigned short vb[8] = {0,0,0,0,0,0,0,0};
    if (quad == 0) {        // k = 0..7
        va[0]=hx; va[1]=hx; va[2]=lx; va[3]=hy; va[4]=hy; va[5]=ly; va[6]=hz; va[7]=hz;
        vb[0]=nhx; vb[1]=nlx; vb[2]=nhx; vb[3]=nhy; vb[4]=nly; vb[5]=nhy; vb[6]=nhz; vb[7]=nlz;
    } else if (quad == 1) { // k = 8..15 (13..15 zero)
        va[0]=lz; va[1]=h2; va[2]=l2; va[3]=ONE; va[4]=ONE;
        vb[0]=nhz; vb[1]=ONE; vb[2]=ONE; vb[3]=h2; vb[4]=l2;
    }                        // quads 2,3: all zero
    uint4 pa, pb;
    pa.x = (unsigned)va[0] | ((unsigned)va[1] << 16);
    pa.y = (unsigned)va[2] | ((unsigned)va[3] << 16);
    pa.z = (unsigned)va[4] | ((unsigned)va[5] << 16);
    pa.w = (unsigned)va[6] | ((unsigned)va[7] << 16);
    pb.x = (unsigned)vb[0] | ((unsigned)vb[1] << 16);
    pb.y = (unsigned)vb[2] | ((unsigned)vb[3] << 16);
    pb.z = (unsigned)vb[4] | ((unsigned)vb[5] << 16);
    pb.w = (unsigned)vb[6] | ((unsigned)vb[7] << 16);
    size_t off = ((size_t)b * NFRAG16 + f) * 64 + lane;
    (cloud ? aT : aS)[off] = pa;
    (cloud ? bT : bS)[off] = pb;
}

// ---- scan: DB frags from LDS (A), queries in regs (B), scalar running min ----
__global__ __launch_bounds__(256, 4) void scan_kernel(
    const uint4* __restrict__ aS, const uint4* __restrict__ bS,
    const uint4* __restrict__ aT, const uint4* __restrict__ bT,
    float* __restrict__ part)   // part[dir][b][ch][query]
{
    __shared__ uint4 ash[CFRAGS * 64];          // 32 KB DB stage
    const int tid = threadIdx.x;
    const int lane = tid & 63, wave = tid >> 6;
    const int qb = blockIdx.x, b = blockIdx.y;
    const int dir = blockIdx.z >> 4, ch = blockIdx.z & (NCHG - 1);

    // dir 0: queries = source (bS), DB = target (aT); dir 1 mirrored.
    const uint4* qfr = dir ? bT : bS;
    const uint4* dfr = dir ? aS : aT;

    // stage DB chunk (32 frags x 64 lanes, 8 uint4/thread, coalesced)
    const uint4* dsrc = dfr + ((size_t)b * NFRAG16 + ch * CFRAGS) * 64;
#pragma unroll
    for (int j = 0; j < 8; j++) ash[tid + j * 256] = dsrc[tid + j * 256];

    // this wave's query fragments (B operand, registers all sweep)
    const uint4* qsrc = qfr + ((size_t)b * NFRAG16 + qb * (WAVES * RF) + wave * RF) * 64 + lane;
    bf16x8 qfrag[RF];
#pragma unroll
    for (int rf = 0; rf < RF; rf++) {
        uint4 t = qsrc[rf * 64];
        qfrag[rf] = *(bf16x8*)&t;
    }

    float vminq[RF];
#pragma unroll
    for (int rf = 0; rf < RF; rf++) vminq[rf] = 1e30f;
    f32x4 zero = {0.f, 0.f, 0.f, 0.f};
    __syncthreads();                            // the block's only barrier

    for (int t = 0; t < CFRAGS; t += 2) {
        bf16x8 a0 = *(bf16x8*)&ash[t * 64 + lane];
        bf16x8 a1 = *(bf16x8*)&ash[(t + 1) * 64 + lane];
#pragma unroll
        for (int rf = 0; rf < RF; rf++) {
            f32x4 dA = __builtin_amdgcn_mfma_f32_16x16x32_bf16(a0, qfrag[rf], zero, 0, 0, 0);
            f32x4 dB = __builtin_amdgcn_mfma_f32_16x16x32_bf16(a1, qfrag[rf], zero, 0, 0, 0);
            float v = vminq[rf];
            v = fminf(fminf(dA[0], dA[1]), v);  // v_min3_f32
            v = fminf(fminf(dA[2], dA[3]), v);
            v = fminf(fminf(dB[0], dB[1]), v);
            v = fminf(fminf(dB[2], dB[3]), v);
            vminq[rf] = v;
        }
    }

    // finalize: lanes lane, lane^16, lane^32, lane^48 hold the same query col
    float* pbase = part + ((size_t)(dir * BB + b) * NCHG + ch) * NP
                 + qb * (WAVES * RF * 16) + wave * (RF * 16);
#pragma unroll
    for (int rf = 0; rf < RF; rf++) {
        float v = vminq[rf];
        v = fminf(v, __shfl_xor(v, 16, 64));
        v = fminf(v, __shfl_xor(v, 32, 64));
        if (lane < 16) pbase[rf * 16 + lane] = v;
    }
}

// ---- reduce: min over DB chunks, weight, sum, atomicAdd ----
__global__ __launch_bounds__(256) void reduce_kernel(
    const float* __restrict__ weights, const float* __restrict__ part,
    float* __restrict__ out)
{
    int tid = threadIdx.x;
    int gid = blockIdx.x * 256 + tid;       // 0 .. 65535
    int dir = gid >> 15;
    int r   = gid & 32767;
    int b   = r >> 13;
    int q   = r & (NP - 1);

    const float* p = part + ((size_t)(dir * BB + b) * NCHG) * NP + q;
    float mn = 1e30f;
#pragma unroll
    for (int i = 0; i < NCHG; i++) mn = fminf(mn, p[(size_t)i * NP]);
    float w = dir ? 1.0f : weights[b * NP + q];
    float v = mn * w * (1.0f / BB);
#pragma unroll
    for (int off = 32; off; off >>= 1) v += __shfl_down(v, off, 64);
    __shared__ float ls[4];
    if ((tid & 63) == 0) ls[tid >> 6] = v;
    __syncthreads();
    if (tid == 0) atomicAdd(out, ls[0] + ls[1] + ls[2] + ls[3]);
}

extern "C" void kernel_launch(void* const* d_in, const int* in_sizes, int n_in,
                              void* d_out, int out_size, void* d_ws, size_t ws_size,
                              hipStream_t stream) {
    const float* src = (const float*)d_in[0];   // (B, N, 3)
    const float* tgt = (const float*)d_in[1];   // (B, M, 3)
    const float* wgt = (const float*)d_in[2];   // (B, N)
    float* out = (float*)d_out;

    char* ws = (char*)d_ws;
    const size_t FRAG_BYTES = (size_t)BB * NFRAG16 * 64 * 16;   // 2 MB each
    uint4* aS = (uint4*)(ws + 0 * FRAG_BYTES);
    uint4* bS = (uint4*)(ws + 1 * FRAG_BYTES);
    uint4* aT = (uint4*)(ws + 2 * FRAG_BYTES);
    uint4* bT = (uint4*)(ws + 3 * FRAG_BYTES);
    float* part = (float*)(ws + 4 * FRAG_BYTES);                // 4 MB

    prep_kernel<<<dim3(1024), dim3(256), 0, stream>>>(src, tgt, aS, bS, aT, bT, out);
    scan_kernel<<<dim3(QBLOCKS, BB, 2 * NCHG), dim3(256), 0, stream>>>(aS, bS, aT, bT, part);
    reduce_kernel<<<dim3(256), dim3(256), 0, stream>>>(wgt, part, out);
}